// Round 6
// baseline (1002.231 us; speedup 1.0000x reference)
//
#include <hip/hip_runtime.h>
#include <math.h>

#define TT 200
#define BB 16384
#define HH 20

// LDS weight store (f32, layer-1 only): [0,1600) W_ih1, [1600,3200) W_hh1,
// [3200,3280) b_ih1+b_hh1
#define SW_IH1 0
#define SW_HH1 1600
#define SW_B1  3200
#define SWN    3280

__device__ double g_bd[3];   // b_dec in f64

// ---------- JAX threefry2x32, key = jax.random.key(42) = [0, 42] ----------
__device__ __forceinline__ void tf2x32(unsigned x0, unsigned x1,
                                       unsigned* o0, unsigned* o1) {
  const unsigned ks0 = 0u, ks1 = 42u;
  const unsigned ks2 = ks0 ^ ks1 ^ 0x1BD11BDAu;
  x0 += ks0; x1 += ks1;
#define ROTL_(v, d) (((v) << (d)) | ((v) >> (32 - (d))))
#define RND_(r) { x0 += x1; x1 = ROTL_(x1, r); x1 ^= x0; }
  RND_(13) RND_(15) RND_(26) RND_(6)
  x0 += ks1; x1 += ks2 + 1u;
  RND_(17) RND_(29) RND_(16) RND_(24)
  x0 += ks2; x1 += ks0 + 2u;
  RND_(13) RND_(15) RND_(26) RND_(6)
  x0 += ks0; x1 += ks1 + 3u;
  RND_(17) RND_(29) RND_(16) RND_(24)
  x0 += ks1; x1 += ks2 + 4u;
  RND_(13) RND_(15) RND_(26) RND_(6)
  x0 += ks2; x1 += ks0 + 5u;
  *o0 = x0; *o1 = x1;
#undef RND_
#undef ROTL_
}

// uniform bits -> gumbel sample (f32 bit manipulation exact; logs in f64)
__device__ __forceinline__ double bits2gumbel(unsigned bits) {
  float f = __uint_as_float((bits >> 9) | 0x3F800000u) - 1.0f;
  float uf = (f > 0.0f) ? f : 1.17549435e-38f;  // max(tiny, f) semantics
  return -log(-log((double)uf));
}

// ---------- f32 activations (HW exp + HW rcp, no clamp / no NR) ----------
// Limits are exact without clamps: exp->inf => rcp->0; exp->0 => rcp(1).
// HW v_rcp_f32 is ~1 ulp; downstream tolerance is ~4e-3 (ref-side f32
// noise dominates), so the Newton step is dropped.
__device__ __forceinline__ float sigm_f(float x) {
  float e = __expf(-x);
  return __builtin_amdgcn_rcpf(1.0f + e);
}
__device__ __forceinline__ float tanh_f(float x) {
  float e = __expf(2.0f * x);
  return 1.0f - 2.0f * __builtin_amdgcn_rcpf(1.0f + e);
}

__global__ void prep_kernel(const float* __restrict__ b_dec) {
  int i = threadIdx.x;
  if (i < 3) g_bd[i] = (double)b_dec[i];
}

// layer-0 chunk: NC units at rows row0..; f32 dots, f32 activations.
// Weights via wave-uniform indices into the original f32 arrays -> s_load
// (SMEM pipe, K$-resident), keeping the LDS pipe free.
template <int NC>
__device__ __forceinline__ void l0_chunk(int row0,
                                         const float* __restrict__ Wih0,
                                         const float* __restrict__ Whh0,
                                         const float* __restrict__ bih0,
                                         const float* __restrict__ bhh0,
                                         float x0, float x1,
                                         const float* hp, float* c_st,
                                         float* dst) {
  float acc[NC][4];
#pragma unroll
  for (int u = 0; u < NC; ++u) {
#pragma unroll
    for (int g = 0; g < 4; ++g) {
      int row = g * 20 + row0 + u;
      float a = bih0[row] + bhh0[row];
      a = fmaf(Wih0[row * 2 + 0], x0, a);
      a = fmaf(Wih0[row * 2 + 1], x1, a);
      acc[u][g] = a;
    }
  }
#pragma unroll
  for (int j = 0; j < HH; ++j) {
    float hj = hp[j];
#pragma unroll
    for (int u = 0; u < NC; ++u)
#pragma unroll
      for (int g = 0; g < 4; ++g)
        acc[u][g] = fmaf(Whh0[(g * 20 + row0 + u) * HH + j], hj, acc[u][g]);
  }
#pragma unroll
  for (int u = 0; u < NC; ++u) {
    float si = sigm_f(acc[u][0]), sf = sigm_f(acc[u][1]);
    float tg = tanh_f(acc[u][2]), so = sigm_f(acc[u][3]);
    float c = fmaf(sf, c_st[u], si * tg);
    c_st[u] = c;
    dst[u] = so * tanh_f(c);
  }
}

// layer-1 gate dots, LDS-weight variant: float4 (b128 uniform broadcast)
// weight reads; rows are 80 B so every 4-element group is 16B-aligned.
__device__ __forceinline__ void l1_gates_lds(int row0,
                                             const float* __restrict__ sw,
                                             const float* hp0,
                                             const float* h1r,
                                             float acc[2][4]) {
#pragma unroll
  for (int u = 0; u < 2; ++u)
#pragma unroll
    for (int g = 0; g < 4; ++g)
      acc[u][g] = sw[SW_B1 + g * 20 + row0 + u];
#pragma unroll
  for (int j4 = 0; j4 < 5; ++j4) {
    float h0 = hp0[4 * j4 + 0], h1 = hp0[4 * j4 + 1];
    float h2 = hp0[4 * j4 + 2], h3 = hp0[4 * j4 + 3];
#pragma unroll
    for (int u = 0; u < 2; ++u)
#pragma unroll
      for (int g = 0; g < 4; ++g) {
        float4 w = *(const float4*)&sw[SW_IH1 + (g * 20 + row0 + u) * HH + 4 * j4];
        acc[u][g] = fmaf(w.x, h0, acc[u][g]);
        acc[u][g] = fmaf(w.y, h1, acc[u][g]);
        acc[u][g] = fmaf(w.z, h2, acc[u][g]);
        acc[u][g] = fmaf(w.w, h3, acc[u][g]);
      }
  }
#pragma unroll
  for (int j4 = 0; j4 < 5; ++j4) {
    float h0 = h1r[4 * j4 + 0], h1 = h1r[4 * j4 + 1];
    float h2 = h1r[4 * j4 + 2], h3 = h1r[4 * j4 + 3];
#pragma unroll
    for (int u = 0; u < 2; ++u)
#pragma unroll
      for (int g = 0; g < 4; ++g) {
        float4 w = *(const float4*)&sw[SW_HH1 + (g * 20 + row0 + u) * HH + 4 * j4];
        acc[u][g] = fmaf(w.x, h0, acc[u][g]);
        acc[u][g] = fmaf(w.y, h1, acc[u][g]);
        acc[u][g] = fmaf(w.z, h2, acc[u][g]);
        acc[u][g] = fmaf(w.w, h3, acc[u][g]);
      }
  }
}

// layer-1 gate dots, SMEM-weight variant: wave-uniform indices into the
// original f32 arrays -> s_load (K$-resident). Same FMA order.
__device__ __forceinline__ void l1_gates_smem(int row0,
                                              const float* __restrict__ Wih1,
                                              const float* __restrict__ Whh1,
                                              const float* __restrict__ bih1,
                                              const float* __restrict__ bhh1,
                                              const float* hp0,
                                              const float* h1r,
                                              float acc[2][4]) {
#pragma unroll
  for (int u = 0; u < 2; ++u)
#pragma unroll
    for (int g = 0; g < 4; ++g) {
      int row = g * 20 + row0 + u;
      acc[u][g] = bih1[row] + bhh1[row];
    }
#pragma unroll
  for (int j = 0; j < HH; ++j) {
    float hj = hp0[j];
#pragma unroll
    for (int u = 0; u < 2; ++u)
#pragma unroll
      for (int g = 0; g < 4; ++g)
        acc[u][g] = fmaf(Wih1[(g * 20 + row0 + u) * HH + j], hj, acc[u][g]);
  }
#pragma unroll
  for (int j = 0; j < HH; ++j) {
    float hj = h1r[j];
#pragma unroll
    for (int u = 0; u < 2; ++u)
#pragma unroll
      for (int g = 0; g < 4; ++g)
        acc[u][g] = fmaf(Whh1[(g * 20 + row0 + u) * HH + j], hj, acc[u][g]);
  }
}

// common layer-1 tail: activations, state update, decoder accumulation (f64)
__device__ __forceinline__ void l1_tail(float acc[2][4], float* c_st,
                                        float* dst,
                                        double wd00, double wd01,
                                        double wd10, double wd11,
                                        double wd20, double wd21,
                                        double* lg) {
#pragma unroll
  for (int u = 0; u < 2; ++u) {
    float si = sigm_f(acc[u][0]), sf = sigm_f(acc[u][1]);
    float tg = tanh_f(acc[u][2]), so = sigm_f(acc[u][3]);
    float c = fmaf(sf, c_st[u], si * tg);
    c_st[u] = c;
    float h = so * tanh_f(c);
    dst[u] = h;
    double hd = (double)h;
    if (u == 0) {
      lg[0] = fma(wd00, hd, lg[0]);
      lg[1] = fma(wd10, hd, lg[1]);
      lg[2] = fma(wd20, hd, lg[2]);
    } else {
      lg[0] = fma(wd01, hd, lg[0]);
      lg[1] = fma(wd11, hd, lg[1]);
      lg[2] = fma(wd21, hd, lg[2]);
    }
  }
}

// 16 waves / 64 elements: waves 0-5 = layer-0 units {4,4,3,3,3,3} (SMEM
// weights); waves 6-10 = layer-1 SMEM-weight waves, waves 11-15 = layer-1
// LDS-weight waves ({2 units each}, pipelined one step behind L0).
// Three memory pipes (SMEM/K$, LDS, VMEM) run in parallel.
__global__ __launch_bounds__(1024, 4) void lstm_wave_kernel(
    const float* __restrict__ x,      // [T,B,2]
    const float* __restrict__ h0_in,  // [2,B,20]
    const float* __restrict__ c0_in,  // [2,B,20]
    const float* __restrict__ Wih0,   // [80,2]
    const float* __restrict__ Whh0,   // [80,20]
    const float* __restrict__ bih0,   // [80]
    const float* __restrict__ bhh0,   // [80]
    const float* __restrict__ Wih1,   // [80,20]
    const float* __restrict__ Whh1,   // [80,20]
    const float* __restrict__ bih1,   // [80]
    const float* __restrict__ bhh1,   // [80]
    const float* __restrict__ Wdec_f, // [3,4000]
    float* __restrict__ out) {
  __shared__ float s_h0[2][64][22];    // stride 22 dwords: 8B-aligned rows,
  __shared__ float s_h1[2][64][22];    // gcd(22,32)=2 -> 2-way = free
  __shared__ double s_logit[10][64][3];
  __shared__ __align__(16) float s_w[SWN];  // layer-1 weights + biases

  const int lane = threadIdx.x & 63;
  const int wv = __builtin_amdgcn_readfirstlane((int)(threadIdx.x >> 6));
  const int eg = blockIdx.x * 64 + lane;

  // stage L1 weights/biases into LDS (one-time)
  for (int i = threadIdx.x; i < SWN; i += 1024) {
    float v;
    if (i < SW_HH1) v = Wih1[i];
    else if (i < SW_B1) v = Whh1[i - SW_HH1];
    else v = bih1[i - SW_B1] + bhh1[i - SW_B1];
    s_w[i] = v;
  }

  const bool isL0 = (wv < 6);
  int u0r, nur;
  if (isL0) {
    if (wv < 2) { u0r = wv * 4; nur = 4; }
    else        { u0r = 8 + (wv - 2) * 3; nur = 3; }
  } else {
    u0r = (wv - 6) * 2; nur = 2;
  }
  const int u0 = __builtin_amdgcn_readfirstlane(u0r);
  const int nu = __builtin_amdgcn_readfirstlane(nur);

  float c_st[4];
  double lg[3] = {0.0, 0.0, 0.0};

  // init: h(-1) into buffer 1 (phases 0/1 read it there)
  {
    const int l = isL0 ? 0 : 1;
#pragma unroll
    for (int u = 0; u < 4; ++u) {
      if (u < nu) {
        c_st[u] = c0_in[l * BB * HH + eg * HH + u0 + u];
        float h = h0_in[l * BB * HH + eg * HH + u0 + u];
        if (isL0) s_h0[1][lane][u0 + u] = h;
        else      s_h1[1][lane][u0 + u] = h;
      }
    }
  }
  __syncthreads();

  const float2* x2 = (const float2*)x;
  const float2* wd2 = (const float2*)Wdec_f;

  // x prefetch register: holds x(t) one full phase ahead.
  float2 xv_cur;
  if (isL0) xv_cur = x2[0 * BB + eg];

  // phase s: L0 computes t=s (s<200): reads h0 buf (s+1)&1, writes s&1.
  //          L1 computes t1=s-1 (s>=1): h0(t1) from t1&1, own h1(t1-1) from
  //          (t1+1)&1, writes h1(t1) -> t1&1.
  for (int s = 0; s <= TT; ++s) {
    if (isL0) {
      if (s < TT) {
        const int rb = (s + 1) & 1;
        const int wb = s & 1;
        float2 xv = xv_cur;
        if (s + 1 < TT) xv_cur = x2[(s + 1) * BB + eg];  // prefetch next step
        float hp[HH];
#pragma unroll
        for (int j2 = 0; j2 < 10; ++j2) {
          float2 v = *(const float2*)&s_h0[rb][lane][2 * j2];
          hp[2 * j2] = v.x; hp[2 * j2 + 1] = v.y;
        }
        float* dst = &s_h0[wb][lane][0];
        if (nu == 4) {
          l0_chunk<2>(u0 + 0, Wih0, Whh0, bih0, bhh0, xv.x, xv.y, hp, c_st + 0, dst + u0 + 0);
          l0_chunk<2>(u0 + 2, Wih0, Whh0, bih0, bhh0, xv.x, xv.y, hp, c_st + 2, dst + u0 + 2);
        } else {
          l0_chunk<2>(u0 + 0, Wih0, Whh0, bih0, bhh0, xv.x, xv.y, hp, c_st + 0, dst + u0 + 0);
          l0_chunk<1>(u0 + 2, Wih0, Whh0, bih0, bhh0, xv.x, xv.y, hp, c_st + 2, dst + u0 + 2);
        }
      }
    } else {
      if (s >= 1) {
        const int t1 = s - 1;
        const int h0b = t1 & 1;
        const int h1rb = (t1 + 1) & 1;
        // W_dec cols for this step: f32 global loads (in-order vmcnt),
        // issued here, consumed at the end of the tail -> fully hidden.
        const int col = t1 * HH + u0;  // u0 even -> float2 aligned
        float2 w0 = wd2[(0    + col) >> 1];
        float2 w1 = wd2[(4000 + col) >> 1];
        float2 w2 = wd2[(8000 + col) >> 1];
        float hp0[HH];
#pragma unroll
        for (int j2 = 0; j2 < 10; ++j2) {
          float2 v = *(const float2*)&s_h0[h0b][lane][2 * j2];
          hp0[2 * j2] = v.x; hp0[2 * j2 + 1] = v.y;
        }
        const float* h1r = &s_h1[h1rb][lane][0];
        float* dst = &s_h1[h0b][lane][0];
        float acc[2][4];
        if (wv < 11) {
          l1_gates_smem(u0, Wih1, Whh1, bih1, bhh1, hp0, h1r, acc);
        } else {
          l1_gates_lds(u0, s_w, hp0, h1r, acc);
        }
        l1_tail(acc, c_st, dst + u0,
                (double)w0.x, (double)w0.y,
                (double)w1.x, (double)w1.y,
                (double)w2.x, (double)w2.y, lg);
      }
    }
    __syncthreads();
  }

  // final states: h(199) in buffer 1 (199&1==1)
  {
    const int l = isL0 ? 0 : 1;
#pragma unroll
    for (int u = 0; u < 4; ++u) {
      if (u < nu) {
        float hfin = isL0 ? s_h0[1][lane][u0 + u] : s_h1[1][lane][u0 + u];
        out[2 * BB + l * BB * HH + eg * HH + u0 + u] = hfin;
        out[2 * BB + 2 * BB * HH + l * BB * HH + eg * HH + u0 + u] = c_st[u];
      }
    }
  }

  if (!isL0) {
    s_logit[wv - 6][lane][0] = lg[0];
    s_logit[wv - 6][lane][1] = lg[1];
    s_logit[wv - 6][lane][2] = lg[2];
  }
  __syncthreads();

  if (wv == 0) {
    double l[3];
#pragma unroll
    for (int a = 0; a < 3; ++a) {
      double v = g_bd[a];
#pragma unroll
      for (int k = 0; k < 10; ++k) v += s_logit[k][lane][a];
      l[a] = v;
    }

    // partitionable 32-bit stream: hi^lo of threefry2x32(key, (0, flat_idx))
    int act = 0;
    double vbest = -1.0e300;
#pragma unroll
    for (int a = 0; a < 3; ++a) {
      unsigned idx = 3u * (unsigned)eg + (unsigned)a;
      unsigned p0, p1;
      tf2x32(0u, idx, &p0, &p1);
      double g = bits2gumbel(p0 ^ p1);
      double v = l[a] + g;
      if (v > vbest) { vbest = v; act = a; }  // strict >: first max (argmax)
    }
    double m = fmax(l[0], fmax(l[1], l[2]));
    double se = exp(l[0] - m) + exp(l[1] - m) + exp(l[2] - m);
    double lp = (l[act] - m) - log(se);
    out[eg] = (float)act;
    out[BB + eg] = (float)lp;
  }
}

extern "C" void kernel_launch(void* const* d_in, const int* in_sizes, int n_in,
                              void* d_out, int out_size, void* d_ws, size_t ws_size,
                              hipStream_t stream) {
  prep_kernel<<<dim3(1), dim3(64), 0, stream>>>((const float*)d_in[12]);
  lstm_wave_kernel<<<dim3(BB / 64), dim3(1024), 0, stream>>>(
      (const float*)d_in[0], (const float*)d_in[1], (const float*)d_in[2],
      (const float*)d_in[3], (const float*)d_in[4],
      (const float*)d_in[5], (const float*)d_in[6],
      (const float*)d_in[7], (const float*)d_in[8],
      (const float*)d_in[9], (const float*)d_in[10],
      (const float*)d_in[11], (float*)d_out);
}

// Round 7
// 933.895 us; speedup vs baseline: 1.0732x; 1.0732x over previous
//
#include <hip/hip_runtime.h>
#include <math.h>

#define TT 200
#define BB 16384
#define HH 20
#define EPB 32   // elements per block (2 blocks/CU -> 2 independent barrier groups)

// s_w layout (f32 element offsets)
#define OW_IH0 0      // 160   W_ih0 [80,2]
#define OW_HH0 160    // 1600  W_hh0 [80,20]
#define OB_0   1760   // 80    b_ih0+b_hh0
#define OW_IH1 1840   // 1600  W_ih1 [80,20]
#define OW_HH1 3440   // 1600  W_hh1 [80,20]
#define OB_1   5040   // 80    b_ih1+b_hh1
#define SWN    5120

__device__ double g_bd[3];   // b_dec in f64

// ---------- JAX threefry2x32, key = jax.random.key(42) = [0, 42] ----------
__device__ __forceinline__ void tf2x32(unsigned x0, unsigned x1,
                                       unsigned* o0, unsigned* o1) {
  const unsigned ks0 = 0u, ks1 = 42u;
  const unsigned ks2 = ks0 ^ ks1 ^ 0x1BD11BDAu;
  x0 += ks0; x1 += ks1;
#define ROTL_(v, d) (((v) << (d)) | ((v) >> (32 - (d))))
#define RND_(r) { x0 += x1; x1 = ROTL_(x1, r); x1 ^= x0; }
  RND_(13) RND_(15) RND_(26) RND_(6)
  x0 += ks1; x1 += ks2 + 1u;
  RND_(17) RND_(29) RND_(16) RND_(24)
  x0 += ks2; x1 += ks0 + 2u;
  RND_(13) RND_(15) RND_(26) RND_(6)
  x0 += ks0; x1 += ks1 + 3u;
  RND_(17) RND_(29) RND_(16) RND_(24)
  x0 += ks1; x1 += ks2 + 4u;
  RND_(13) RND_(15) RND_(26) RND_(6)
  x0 += ks2; x1 += ks0 + 5u;
  *o0 = x0; *o1 = x1;
#undef RND_
#undef ROTL_
}

// uniform bits -> gumbel sample (f32 bit manipulation exact; logs in f64)
__device__ __forceinline__ double bits2gumbel(unsigned bits) {
  float f = __uint_as_float((bits >> 9) | 0x3F800000u) - 1.0f;
  float uf = (f > 0.0f) ? f : 1.17549435e-38f;  // max(tiny, f) semantics
  return -log(-log((double)uf));
}

// ---------- f32 activations (HW exp + HW rcp, no clamp / no NR) ----------
__device__ __forceinline__ float sigm_f(float x) {
  float e = __expf(-x);
  return __builtin_amdgcn_rcpf(1.0f + e);
}
__device__ __forceinline__ float tanh_f(float x) {
  float e = __expf(2.0f * x);
  return 1.0f - 2.0f * __builtin_amdgcn_rcpf(1.0f + e);
}

__global__ void prep_kernel(const float* __restrict__ b_dec) {
  int i = threadIdx.x;
  if (i < 3) g_bd[i] = (double)b_dec[i];
}

// layer-0 chunk: NC units at per-lane base u0; weights from LDS via float4
// (2 distinct addresses per wave -> 2-way broadcast, measured free).
// FMA order per accumulator: bias, ih j asc, hh j asc — identical to r5.
template <int NC>
__device__ __forceinline__ void l0_chunk(const float* __restrict__ sw, int u0,
                                         float x0, float x1,
                                         const float* hp, float* c_st,
                                         float* dst) {
  float acc[NC][4];
#pragma unroll
  for (int u = 0; u < NC; ++u)
#pragma unroll
    for (int g = 0; g < 4; ++g) {
      int row = g * 20 + u0 + u;
      float2 wi = *(const float2*)&sw[OW_IH0 + row * 2];
      float a = sw[OB_0 + row];
      a = fmaf(wi.x, x0, a);
      a = fmaf(wi.y, x1, a);
      acc[u][g] = a;
    }
#pragma unroll
  for (int j4 = 0; j4 < 5; ++j4) {
    float h0v = hp[4 * j4 + 0], h1v = hp[4 * j4 + 1];
    float h2v = hp[4 * j4 + 2], h3v = hp[4 * j4 + 3];
#pragma unroll
    for (int u = 0; u < NC; ++u)
#pragma unroll
      for (int g = 0; g < 4; ++g) {
        float4 w = *(const float4*)&sw[OW_HH0 + (g * 20 + u0 + u) * HH + 4 * j4];
        acc[u][g] = fmaf(w.x, h0v, acc[u][g]);
        acc[u][g] = fmaf(w.y, h1v, acc[u][g]);
        acc[u][g] = fmaf(w.z, h2v, acc[u][g]);
        acc[u][g] = fmaf(w.w, h3v, acc[u][g]);
      }
  }
#pragma unroll
  for (int u = 0; u < NC; ++u) {
    float si = sigm_f(acc[u][0]), sf = sigm_f(acc[u][1]);
    float tg = tanh_f(acc[u][2]), so = sigm_f(acc[u][3]);
    float c = fmaf(sf, c_st[u], si * tg);
    c_st[u] = c;
    dst[u] = so * tanh_f(c);
  }
}

// layer-1 chunk: 2 units at per-lane base u0; weights from LDS via float4;
// decoder accumulation in f64.
__device__ __forceinline__ void l1_chunk2(const float* __restrict__ sw, int u0,
                                          const float* hp0, const float* h1r,
                                          float* c_st, float* dst,
                                          double wd00, double wd01,
                                          double wd10, double wd11,
                                          double wd20, double wd21,
                                          double* lg) {
  float acc[2][4];
#pragma unroll
  for (int u = 0; u < 2; ++u)
#pragma unroll
    for (int g = 0; g < 4; ++g)
      acc[u][g] = sw[OB_1 + g * 20 + u0 + u];
#pragma unroll
  for (int j4 = 0; j4 < 5; ++j4) {
    float h0v = hp0[4 * j4 + 0], h1v = hp0[4 * j4 + 1];
    float h2v = hp0[4 * j4 + 2], h3v = hp0[4 * j4 + 3];
#pragma unroll
    for (int u = 0; u < 2; ++u)
#pragma unroll
      for (int g = 0; g < 4; ++g) {
        float4 w = *(const float4*)&sw[OW_IH1 + (g * 20 + u0 + u) * HH + 4 * j4];
        acc[u][g] = fmaf(w.x, h0v, acc[u][g]);
        acc[u][g] = fmaf(w.y, h1v, acc[u][g]);
        acc[u][g] = fmaf(w.z, h2v, acc[u][g]);
        acc[u][g] = fmaf(w.w, h3v, acc[u][g]);
      }
  }
#pragma unroll
  for (int j4 = 0; j4 < 5; ++j4) {
    float h0v = h1r[4 * j4 + 0], h1v = h1r[4 * j4 + 1];
    float h2v = h1r[4 * j4 + 2], h3v = h1r[4 * j4 + 3];
#pragma unroll
    for (int u = 0; u < 2; ++u)
#pragma unroll
      for (int g = 0; g < 4; ++g) {
        float4 w = *(const float4*)&sw[OW_HH1 + (g * 20 + u0 + u) * HH + 4 * j4];
        acc[u][g] = fmaf(w.x, h0v, acc[u][g]);
        acc[u][g] = fmaf(w.y, h1v, acc[u][g]);
        acc[u][g] = fmaf(w.z, h2v, acc[u][g]);
        acc[u][g] = fmaf(w.w, h3v, acc[u][g]);
      }
  }
#pragma unroll
  for (int u = 0; u < 2; ++u) {
    float si = sigm_f(acc[u][0]), sf = sigm_f(acc[u][1]);
    float tg = tanh_f(acc[u][2]), so = sigm_f(acc[u][3]);
    float c = fmaf(sf, c_st[u], si * tg);
    c_st[u] = c;
    float h = so * tanh_f(c);
    dst[u] = h;
    double hd = (double)h;
    if (u == 0) {
      lg[0] = fma(wd00, hd, lg[0]);
      lg[1] = fma(wd10, hd, lg[1]);
      lg[2] = fma(wd20, hd, lg[2]);
    } else {
      lg[0] = fma(wd01, hd, lg[0]);
      lg[1] = fma(wd11, hd, lg[1]);
      lg[2] = fma(wd21, hd, lg[2]);
    }
  }
}

// 8 waves / 32 elements / 512 blocks (2 blocks per CU = 2 independent
// barrier groups). Lane = (element = lane&31, half = lane>>5). The 16
// unit-chunks map to (wave, half): wave 0 = L0 {4,4}; waves 1-2 = L0 {3,3};
// waves 3-7 = L1 {2,2}, pipelined one step behind.
__global__ __launch_bounds__(512, 4) void lstm_wave_kernel(
    const float* __restrict__ x,      // [T,B,2]
    const float* __restrict__ h0_in,  // [2,B,20]
    const float* __restrict__ c0_in,  // [2,B,20]
    const float* __restrict__ Wih0,   // [80,2]
    const float* __restrict__ Whh0,   // [80,20]
    const float* __restrict__ bih0,   // [80]
    const float* __restrict__ bhh0,   // [80]
    const float* __restrict__ Wih1,   // [80,20]
    const float* __restrict__ Whh1,   // [80,20]
    const float* __restrict__ bih1,   // [80]
    const float* __restrict__ bhh1,   // [80]
    const float* __restrict__ Wdec_f, // [3,4000]
    float* __restrict__ out) {
  __shared__ float s_h0[2][EPB][22];   // stride 22 dwords
  __shared__ float s_h1[2][EPB][22];
  __shared__ double s_logit[10][EPB][3];
  __shared__ __align__(16) float s_w[SWN];  // all gate weights + biases

  const int tid = threadIdx.x;
  const int lane = tid & 63;
  const int wv = __builtin_amdgcn_readfirstlane((int)(tid >> 6));
  const int e = lane & 31;
  const int hf = lane >> 5;
  const int eg = blockIdx.x * EPB + e;

  // stage all gate weights/biases into LDS (one-time)
  for (int i = tid; i < SWN; i += 512) {
    float v;
    if (i < OW_HH0) v = Wih0[i];
    else if (i < OB_0) v = Whh0[i - OW_HH0];
    else if (i < OW_IH1) v = bih0[i - OB_0] + bhh0[i - OB_0];
    else if (i < OW_HH1) v = Wih1[i - OW_IH1];
    else if (i < OB_1) v = Whh1[i - OW_HH1];
    else v = bih1[i - OB_1] + bhh1[i - OB_1];
    s_w[i] = v;
  }

  const bool isL0 = (wv < 3);
  int u0, nu;  // u0 is PER-LANE (half-dependent); nu is wave-uniform
  if (isL0) {
    if (wv == 0) { u0 = hf * 4;               nu = 4; }
    else         { u0 = 8 + (wv - 1) * 6 + hf * 3; nu = 3; }
  } else {
    u0 = (wv - 3) * 4 + hf * 2; nu = 2;
  }

  float c_st[4];
  double lg[3] = {0.0, 0.0, 0.0};

  // init: h(-1) into buffer 1 (phases 0/1 read it there)
  {
    const int l = isL0 ? 0 : 1;
#pragma unroll
    for (int u = 0; u < 4; ++u) {
      if (u < nu) {
        c_st[u] = c0_in[l * BB * HH + eg * HH + u0 + u];
        float h = h0_in[l * BB * HH + eg * HH + u0 + u];
        if (isL0) s_h0[1][e][u0 + u] = h;
        else      s_h1[1][e][u0 + u] = h;
      }
    }
  }
  __syncthreads();

  const float2* x2 = (const float2*)x;
  const float2* wd2 = (const float2*)Wdec_f;

  // x prefetch register: holds x(t) one full phase ahead.
  float2 xv_cur;
  if (isL0) xv_cur = x2[0 * BB + eg];

  // phase s: L0 computes t=s (s<200): reads h0 buf (s+1)&1, writes s&1.
  //          L1 computes t1=s-1 (s>=1): h0(t1) from t1&1, own h1(t1-1) from
  //          (t1+1)&1, writes h1(t1) -> t1&1.
  for (int s = 0; s <= TT; ++s) {
    if (isL0) {
      if (s < TT) {
        const int rb = (s + 1) & 1;
        const int wb = s & 1;
        float2 xv = xv_cur;
        if (s + 1 < TT) xv_cur = x2[(s + 1) * BB + eg];  // prefetch next step
        float hp[HH];
#pragma unroll
        for (int j2 = 0; j2 < 10; ++j2) {
          float2 v = *(const float2*)&s_h0[rb][e][2 * j2];
          hp[2 * j2] = v.x; hp[2 * j2 + 1] = v.y;
        }
        float* dst = &s_h0[wb][e][u0];
        if (wv == 0) l0_chunk<4>(s_w, u0, xv.x, xv.y, hp, c_st, dst);
        else         l0_chunk<3>(s_w, u0, xv.x, xv.y, hp, c_st, dst);
      }
    } else {
      if (s >= 1) {
        const int t1 = s - 1;
        const int h0b = t1 & 1;
        const int h1rb = (t1 + 1) & 1;
        // W_dec cols for this step: f32 global loads (in-order vmcnt),
        // issued here, consumed at the end of the tail -> fully hidden.
        const int col = t1 * HH + u0;  // u0 even -> float2 aligned
        float2 w0 = wd2[(0    + col) >> 1];
        float2 w1 = wd2[(4000 + col) >> 1];
        float2 w2 = wd2[(8000 + col) >> 1];
        float hp0[HH];
#pragma unroll
        for (int j2 = 0; j2 < 10; ++j2) {
          float2 v = *(const float2*)&s_h0[h0b][e][2 * j2];
          hp0[2 * j2] = v.x; hp0[2 * j2 + 1] = v.y;
        }
        const float* h1r = &s_h1[h1rb][e][0];
        float* dst = &s_h1[h0b][e][u0];
        l1_chunk2(s_w, u0, hp0, h1r, c_st, dst,
                  (double)w0.x, (double)w0.y,
                  (double)w1.x, (double)w1.y,
                  (double)w2.x, (double)w2.y, lg);
      }
    }
    __syncthreads();
  }

  // final states: h(199) in buffer 1 (199&1==1)
  {
    const int l = isL0 ? 0 : 1;
#pragma unroll
    for (int u = 0; u < 4; ++u) {
      if (u < nu) {
        float hfin = isL0 ? s_h0[1][e][u0 + u] : s_h1[1][e][u0 + u];
        out[2 * BB + l * BB * HH + eg * HH + u0 + u] = hfin;
        out[2 * BB + 2 * BB * HH + l * BB * HH + eg * HH + u0 + u] = c_st[u];
      }
    }
  }

  if (!isL0) {
    const int k = (wv - 3) * 2 + hf;  // == u0/2, matches old k = wv-6 order
    s_logit[k][e][0] = lg[0];
    s_logit[k][e][1] = lg[1];
    s_logit[k][e][2] = lg[2];
  }
  __syncthreads();

  if (wv == 0 && hf == 0) {
    double l[3];
#pragma unroll
    for (int a = 0; a < 3; ++a) {
      double v = g_bd[a];
#pragma unroll
      for (int k = 0; k < 10; ++k) v += s_logit[k][e][a];
      l[a] = v;
    }

    // partitionable 32-bit stream: hi^lo of threefry2x32(key, (0, flat_idx))
    int act = 0;
    double vbest = -1.0e300;
#pragma unroll
    for (int a = 0; a < 3; ++a) {
      unsigned idx = 3u * (unsigned)eg + (unsigned)a;
      unsigned p0, p1;
      tf2x32(0u, idx, &p0, &p1);
      double g = bits2gumbel(p0 ^ p1);
      double v = l[a] + g;
      if (v > vbest) { vbest = v; act = a; }  // strict >: first max (argmax)
    }
    double m = fmax(l[0], fmax(l[1], l[2]));
    double se = exp(l[0] - m) + exp(l[1] - m) + exp(l[2] - m);
    double lp = (l[act] - m) - log(se);
    out[eg] = (float)act;
    out[BB + eg] = (float)lp;
  }
}

extern "C" void kernel_launch(void* const* d_in, const int* in_sizes, int n_in,
                              void* d_out, int out_size, void* d_ws, size_t ws_size,
                              hipStream_t stream) {
  prep_kernel<<<dim3(1), dim3(64), 0, stream>>>((const float*)d_in[12]);
  lstm_wave_kernel<<<dim3(BB / EPB), dim3(512), 0, stream>>>(
      (const float*)d_in[0], (const float*)d_in[1], (const float*)d_in[2],
      (const float*)d_in[3], (const float*)d_in[4],
      (const float*)d_in[5], (const float*)d_in[6],
      (const float*)d_in[7], (const float*)d_in[8],
      (const float*)d_in[9], (const float*)d_in[10],
      (const float*)d_in[11], (float*)d_out);
}